// Round 1
// baseline (9.856 us; speedup 1.0000x reference)
//
#include <hip/hip_runtime.h>
#include <hip/hip_bf16.h>

// ARIMA-collapse kernel.
// Reference facts exploited:
//  - ma_term is identically zero (e_window never updated) -> w_ma unused
//  - D=1 differencing + final cumsum -> only x_enc[:, 4087:4096, :] matters
//  - per-(b,c) scalar AR(8) recursion, 96 steps, then running-sum + last value
//
// Shapes (hardcoded per reference): B=64, S=4096, C=64, P=8, PRED_LEN=96.
// Output: (B, 96, C) float32.

#define B 64
#define S 4096
#define C 64
#define PRED 96

__global__ __launch_bounds__(256) void arima_kernel(const float* __restrict__ x_enc,
                                                    const float* __restrict__ w_ar,
                                                    float* __restrict__ out) {
    int tid = blockIdx.x * blockDim.x + threadIdx.x;   // 0 .. B*C-1
    if (tid >= B * C) return;
    int b = tid >> 6;          // /64
    int c = tid & 63;

    const float* xb = x_enc + (size_t)b * S * C + c;

    // Load the last 9 x_enc values along time; form the 8 trailing diffs.
    // window[p] = x_enc[4088+p] - x_enc[4087+p], p=0..7
    float w0, w1, w2, w3, w4, w5, w6, w7;
    float prev = xb[(size_t)4087 * C];
    float cur;
    cur = xb[(size_t)4088 * C]; w0 = cur - prev; prev = cur;
    cur = xb[(size_t)4089 * C]; w1 = cur - prev; prev = cur;
    cur = xb[(size_t)4090 * C]; w2 = cur - prev; prev = cur;
    cur = xb[(size_t)4091 * C]; w3 = cur - prev; prev = cur;
    cur = xb[(size_t)4092 * C]; w4 = cur - prev; prev = cur;
    cur = xb[(size_t)4093 * C]; w5 = cur - prev; prev = cur;
    cur = xb[(size_t)4094 * C]; w6 = cur - prev; prev = cur;
    cur = xb[(size_t)4095 * C]; w7 = cur - prev; prev = cur;
    // prev == x_enc[b, 4095, c] : cumsum base

    // AR coefficients (uniform across threads; L2/L1 broadcast).
    float a0 = w_ar[0], a1 = w_ar[1], a2 = w_ar[2], a3 = w_ar[3];
    float a4 = w_ar[4], a5 = w_ar[5], a6 = w_ar[6], a7 = w_ar[7];

    float acc = prev;
    float* ob = out + (size_t)b * PRED * C + c;

#pragma unroll
    for (int t = 0; t < PRED; ++t) {
        // Match reference reduction order: einsum sums p=0..7 sequentially.
        float nv = a0 * w0;
        nv += a1 * w1;
        nv += a2 * w2;
        nv += a3 * w3;
        nv += a4 * w4;
        nv += a5 * w5;
        nv += a6 * w6;
        nv += a7 * w7;
        // shift window left, append new
        w0 = w1; w1 = w2; w2 = w3; w3 = w4; w4 = w5; w5 = w6; w6 = w7; w7 = nv;
        acc += nv;
        ob[(size_t)t * C] = acc;
    }
}

extern "C" void kernel_launch(void* const* d_in, const int* in_sizes, int n_in,
                              void* d_out, int out_size, void* d_ws, size_t ws_size,
                              hipStream_t stream) {
    const float* x_enc = (const float*)d_in[0];
    const float* w_ar  = (const float*)d_in[4];
    float* out = (float*)d_out;

    int total = B * C;                 // 4096 threads
    int block = 256;
    int grid = (total + block - 1) / block;   // 16 blocks
    arima_kernel<<<grid, block, 0, stream>>>(x_enc, w_ar, out);
}